// Round 9
// baseline (248.849 us; speedup 1.0000x reference)
//
#include <hip/hip_runtime.h>

#define DEVI __device__ __forceinline__

typedef unsigned short u16;
typedef unsigned int u32;
typedef __attribute__((ext_vector_type(8))) __bf16 bf16x8;
typedef __attribute__((ext_vector_type(2))) __bf16 bf16x2;
typedef __attribute__((ext_vector_type(4))) float f32x4;
typedef __attribute__((ext_vector_type(16))) float f32x16;
typedef __attribute__((ext_vector_type(4))) u32 u32x4;

DEVI u16 f2bf(float f){
  u32 u = __float_as_uint(f);
  return (u16)((u + 0x7FFFu + ((u >> 16) & 1u)) >> 16);
}
DEVI u32 pk2(float lo, float hi){
  bf16x2 t; t[0] = (__bf16)lo; t[1] = (__bf16)hi;
  return __builtin_bit_cast(u32, t);
}

// ------ fused pre: gnstat (blocks 0..511) + weight cast (blocks 512..1535) ------
__global__ __launch_bounds__(256) void pre_kernel(const float* __restrict__ x,
                                                  float2* __restrict__ pstat,
                                                  const float* __restrict__ wq,
                                                  const float* __restrict__ wo,
                                                  u16* __restrict__ wqb,
                                                  u16* __restrict__ wob){
  int bid = blockIdx.x, tid = threadIdx.x;
  if (bid < 512){
    int bg = bid >> 2, qt = bid & 3;
    const float4* xin = (const float4*)(x + (size_t)bg*32768 + qt*8192);
    float s1 = 0.f, s2 = 0.f;
    #pragma unroll
    for (int i = 0; i < 8; ++i){
      float4 v = xin[tid + i*256];
      s1 += v.x + v.y + v.z + v.w;
      s2 += v.x*v.x + v.y*v.y + v.z*v.z + v.w*v.w;
    }
    __shared__ float red[8];
    int lane = tid & 63, w = tid >> 6;
    for (int off = 32; off; off >>= 1){
      s1 += __shfl_down(s1, off);
      s2 += __shfl_down(s2, off);
    }
    if (lane == 0){ red[w] = s1; red[4 + w] = s2; }
    __syncthreads();
    if (tid == 0){
      pstat[bid] = make_float2(red[0]+red[1]+red[2]+red[3],
                               red[4]+red[5]+red[6]+red[7]);
    }
  } else {
    int t = (bid - 512) * 256 + tid;          // 262144 float4 tasks
    const int NQ4 = (1536*512)/4;             // 196608
    float4 v; u16* dst;
    if (t < NQ4){ v = ((const float4*)wq)[t]; dst = wqb + t*4; }
    else        { int u_ = t - NQ4; v = ((const float4*)wo)[u_]; dst = wob + u_*4; }
    ushort4 s;
    s.x = f2bf(v.x); s.y = f2bf(v.y); s.z = f2bf(v.z); s.w = f2bf(v.w);
    *(ushort4*)dst = s;
  }
}

// ------- normalize + transpose (group stats inlined from pstat) -------
__global__ __launch_bounds__(256) void normtrans_kernel(const float* __restrict__ x,
                                                        const float2* __restrict__ pstat,
                                                        const float* __restrict__ gw,
                                                        const float* __restrict__ gb,
                                                        u16* __restrict__ nxT){
  int b = blockIdx.z, c0 = blockIdx.y * 64, l0 = blockIdx.x * 64;
  __shared__ u16 T[64][72];
  int tid = threadIdx.x;
  #pragma unroll
  for (int rep = 0; rep < 2; ++rep){
    int task = tid + rep*256;
    int r = task >> 3, cc = task & 7;          // channel row r, l-chunk cc
    int ch = c0 + r;
    int bg = b*32 + (ch >> 4);
    float s1 = 0.f, s2 = 0.f;
    #pragma unroll
    for (int i = 0; i < 4; ++i){
      float2 p = pstat[bg*4 + i];
      s1 += p.x; s2 += p.y;
    }
    float mu = s1 * (1.f/32768.f);
    float rsg = rsqrtf(s2 * (1.f/32768.f) - mu*mu + 1e-5f);
    float ga = gw[ch] * rsg;
    float be = gb[ch] - mu * ga;
    const float4* src = (const float4*)(x + ((size_t)(b*512 + ch))*2048 + l0 + cc*8);
    float4 v0 = src[0], v1 = src[1];
    ushort4 o0, o1;
    o0.x = f2bf(v0.x*ga + be); o0.y = f2bf(v0.y*ga + be);
    o0.z = f2bf(v0.z*ga + be); o0.w = f2bf(v0.w*ga + be);
    o1.x = f2bf(v1.x*ga + be); o1.y = f2bf(v1.y*ga + be);
    o1.z = f2bf(v1.z*ga + be); o1.w = f2bf(v1.w*ga + be);
    *(ushort4*)&T[r][cc*8]     = o0;
    *(ushort4*)&T[r][cc*8 + 4] = o1;
  }
  __syncthreads();
  #pragma unroll
  for (int rep = 0; rep < 2; ++rep){
    int task = tid + rep*256;
    int r = task >> 3, cc = task & 7;          // r = local l, cc = c-chunk
    u16 tmp[8];
    #pragma unroll
    for (int i = 0; i < 8; ++i) tmp[i] = T[cc*8 + i][r];
    *(uint4*)(nxT + ((size_t)(b*2048 + l0 + r))*512 + c0 + cc*8) = *(uint4*)tmp;
  }
}

// ---------------- GEMM: C[o][l] = sum_c A[o][c] * B[l][c]^T  (bf16 MFMA) ----
// BK=64 staged per barrier pair.
// MODE 0 epilogue: q -> qT [b][h][l][64] (scaled); k -> kF, v -> vF fragment order.
// MODE 1: epilogue adds b_out[o] + x residual, writes fp32 d_out[b][o][l].
template<int MODE>
__global__ __launch_bounds__(256) void gemm_kernel(const u16* __restrict__ A,
                                                   const u16* __restrict__ Bm,
                                                   u16* __restrict__ q_o,
                                                   u16* __restrict__ k_o,
                                                   u16* __restrict__ v_o,
                                                   const float* __restrict__ bo,
                                                   const float* __restrict__ xres,
                                                   float* __restrict__ out){
  int b  = blockIdx.z;
  int n0 = blockIdx.x * 128, m0 = blockIdx.y * 128;
  int tid = threadIdx.x, w = tid >> 6, lane = tid & 63, lq = lane >> 4, lr = lane & 15;
  int wm = (w >> 1) * 64, wn = (w & 1) * 64;
  __shared__ u16 Al[2][128][40], Bl[2][128][40];
  f32x4 acc[4][4] = {};
  const u16* Bb = Bm + (size_t)b * 2048 * 512;

  for (int k0 = 0; k0 < 512; k0 += 64){
    #pragma unroll
    for (int rep = 0; rep < 4; ++rep){
      int task = tid + rep*256;                // 1024 tasks: 128 rows x 8 kc
      int row = task >> 3, kc = task & 7;
      *(uint4*)&Al[kc>>2][row][(kc&3)*8] = *(const uint4*)(A  + (size_t)(m0+row)*512 + k0 + kc*8);
      *(uint4*)&Bl[kc>>2][row][(kc&3)*8] = *(const uint4*)(Bb + (size_t)(n0+row)*512 + k0 + kc*8);
    }
    __syncthreads();
    #pragma unroll
    for (int half = 0; half < 2; ++half){
      bf16x8 af[4], bfr[4];
      #pragma unroll
      for (int i = 0; i < 4; ++i) af[i]  = *(const bf16x8*)&Al[half][wm + i*16 + lr][lq*8];
      #pragma unroll
      for (int j = 0; j < 4; ++j) bfr[j] = *(const bf16x8*)&Bl[half][wn + j*16 + lr][lq*8];
      #pragma unroll
      for (int i = 0; i < 4; ++i)
        #pragma unroll
        for (int j = 0; j < 4; ++j)
          acc[i][j] = __builtin_amdgcn_mfma_f32_16x16x32_bf16(af[i], bfr[j], acc[i][j], 0, 0, 0);
    }
    __syncthreads();
  }

  if (MODE == 0){
    const float QSCALE = 0.125f * 1.4426950408889634f;   // fold log2e for exp2 softmax
    #pragma unroll
    for (int i = 0; i < 4; ++i){
      int o0  = m0 + wm + i*16 + lq*4;          // 4 consecutive o, aligned
      int cls = o0 >> 9;                        // 0=q 1=k 2=v
      int hh  = (o0 >> 6) & 7;
      int d0  = o0 & 63;
      size_t hbase = (size_t)(b*8+hh) * 2048 * 64;
      #pragma unroll
      for (int j = 0; j < 4; ++j){
        int l = n0 + wn + j*16 + lr;            // column index (seq pos / k-idx)
        f32x4 v = acc[i][j];
        if (cls == 0){
          ushort4 s;
          s.x = f2bf(v[0]*QSCALE); s.y = f2bf(v[1]*QSCALE);
          s.z = f2bf(v[2]*QSCALE); s.w = f2bf(v[3]*QSCALE);
          *(ushort4*)(q_o + hbase + (size_t)l*64 + d0) = s;
        } else if (cls == 1){
          size_t off = (size_t)(((l>>5)*4 + (d0>>4)))*512
                     + ((d0>>3)&1)*256 + (l&31)*8 + (d0&7);
          ushort4 s;
          s.x = f2bf(v[0]); s.y = f2bf(v[1]); s.z = f2bf(v[2]); s.w = f2bf(v[3]);
          *(ushort4*)(k_o + hbase + off) = s;
        } else {
          size_t off = (size_t)(((l>>4)*2 + (d0>>5)))*512
                     + ((l>>3)&1)*256 + (l&7);
          #pragma unroll
          for (int r = 0; r < 4; ++r)
            v_o[hbase + off + ((d0+r)&31)*8] = f2bf(v[r]);
        }
      }
    }
  } else {
    #pragma unroll
    for (int i = 0; i < 4; ++i){
      int o0 = m0 + wm + i*16 + lq*4;
      #pragma unroll
      for (int j = 0; j < 4; ++j){
        int l = n0 + wn + j*16 + lr;
        #pragma unroll
        for (int r = 0; r < 4; ++r){
          int o = o0 + r;
          size_t idx = ((size_t)b*512 + o)*2048 + l;
          out[idx] = acc[i][j][r] + bo[o] + xres[idx];
        }
      }
    }
  }
}

// ------- flash attention: 32x32 MFMA, no staging LDS, K-split x2 ----------
// Each wave: 32 q-rows x half the K range. Wave pairs merge online-softmax
// states (m, lsum, O) via one LDS exchange at the end (exact merge).
__global__ __launch_bounds__(256, 4) void attn_kernel(const u16* __restrict__ qT,
                                                      const u16* __restrict__ kF,
                                                      const u16* __restrict__ vF,
                                                      u16* __restrict__ ao){
  int flat = blockIdx.x;              // 0..1023
  int xcd = flat & 7, tt = flat >> 3; // 4 heads per XCD for K/V L2 locality
  int bh = xcd*4 + (tt & 3);          // 0..31
  int qp = tt >> 2;                   // 0..31 (64 q rows per block)
  int tid = threadIdx.x, w = tid >> 6, l = tid & 63;
  int l31 = l & 31, h = l >> 5;
  int qg = w >> 1, kh = w & 1;        // q-subgroup, k-half
  int q0 = qp*64 + qg*32;
  size_t hoff = (size_t)bh * 2048 * 64;
  __shared__ float smrg[2][64][40];   // odd-wave states for merge

  // Q as B-operand: B[col=q=l31][kc=8h+e] = Q[q0+l31][ds*16+8h+e]
  const u16* qp_ = qT + hoff + (size_t)(q0 + l31)*64 + 8*h;
  bf16x8 qf0 = *(const bf16x8*)(qp_);
  bf16x8 qf1 = *(const bf16x8*)(qp_ + 16);
  bf16x8 qf2 = *(const bf16x8*)(qp_ + 32);
  bf16x8 qf3 = *(const bf16x8*)(qp_ + 48);

  const u16* kbase = kF + hoff + (size_t)l*8;
  const u16* vbase = vF + hoff + (size_t)l*8;

  f32x16 o0 = {}, o1 = {};
  float m = -1e30f, lsum = 0.f;

  bf16x8 kA0,kA1,kA2,kA3, kB0,kB1,kB2,kB3;
  bf16x8 vA0,vA1,vA2,vA3, vB0,vB1,vB2,vB3;
  f32x16 sA, sB;
  bf16x8 Bf0, Bf1;

#define LDK(P, t) { const u16* kt_ = kbase + (t)*2048;                         \
    P##0 = *(const bf16x8*)(kt_);        P##1 = *(const bf16x8*)(kt_ + 512);   \
    P##2 = *(const bf16x8*)(kt_ + 1024); P##3 = *(const bf16x8*)(kt_ + 1536); }
#define LDV(P, t) { const u16* vt_ = vbase + (t)*2048;                         \
    P##0 = *(const bf16x8*)(vt_);        P##1 = *(const bf16x8*)(vt_ + 512);   \
    P##2 = *(const bf16x8*)(vt_ + 1024); P##3 = *(const bf16x8*)(vt_ + 1536); }
#define QKT(S, P) {                                                            \
    S = (f32x16){};                                                            \
    __builtin_amdgcn_s_setprio(1);                                             \
    S = __builtin_amdgcn_mfma_f32_32x32x16_bf16(P##0, qf0, S, 0, 0, 0);        \
    S = __builtin_amdgcn_mfma_f32_32x32x16_bf16(P##1, qf1, S, 0, 0, 0);        \
    S = __builtin_amdgcn_mfma_f32_32x32x16_bf16(P##2, qf2, S, 0, 0, 0);        \
    S = __builtin_amdgcn_mfma_f32_32x32x16_bf16(P##3, qf3, S, 0, 0, 0);        \
    __builtin_amdgcn_s_setprio(0); }
#define SMAX(S) { \
    float c0 = fmaxf(S[0],S[1]),  c1 = fmaxf(S[2],S[3]);                       \
    float c2 = fmaxf(S[4],S[5]),  c3 = fmaxf(S[6],S[7]);                       \
    float c4 = fmaxf(S[8],S[9]),  c5 = fmaxf(S[10],S[11]);                     \
    float c6 = fmaxf(S[12],S[13]),c7 = fmaxf(S[14],S[15]);                     \
    c0 = fmaxf(c0,c1); c2 = fmaxf(c2,c3); c4 = fmaxf(c4,c5); c6 = fmaxf(c6,c7);\
    c0 = fmaxf(c0,c2); c4 = fmaxf(c4,c6); c0 = fmaxf(c0,c4);                   \
    c0 = fmaxf(c0, __shfl_xor(c0, 32));                                        \
    if (__any(c0 > m + 8.f)){                                                  \
      float nm = fmaxf(m, c0);                                                 \
      float alpha = __builtin_amdgcn_exp2f(m - nm);                            \
      m = nm; lsum *= alpha;                                                   \
      _Pragma("unroll")                                                        \
      for (int i = 0; i < 16; ++i){ o0[i] *= alpha; o1[i] *= alpha; }          \
    }                                                                          \
    float p[16];                                                               \
    _Pragma("unroll")                                                          \
    for (int i = 0; i < 16; ++i) p[i] = __builtin_amdgcn_exp2f(S[i] - m);      \
    float t0 = p[0]+p[1],  t1 = p[2]+p[3],  t2 = p[4]+p[5],  t3 = p[6]+p[7];   \
    float t4 = p[8]+p[9],  t5 = p[10]+p[11],t6 = p[12]+p[13],t7 = p[14]+p[15]; \
    t0 += t1; t2 += t3; t4 += t5; t6 += t7; t0 += t2; t4 += t6; t0 += t4;      \
    lsum += t0 + __shfl_xor(t0, 32);                                           \
    u32 a0 = pk2(p[0],p[1]),   a1 = pk2(p[2],p[3]);                            \
    u32 a2 = pk2(p[4],p[5]),   a3 = pk2(p[6],p[7]);                            \
    u32 a4 = pk2(p[8],p[9]),   a5 = pk2(p[10],p[11]);                          \
    u32 a6 = pk2(p[12],p[13]), a7 = pk2(p[14],p[15]);                          \
    u32 x0 = __shfl_xor((int)a0,32), x1 = __shfl_xor((int)a1,32);              \
    u32 x2 = __shfl_xor((int)a2,32), x3 = __shfl_xor((int)a3,32);              \
    u32 x4 = __shfl_xor((int)a4,32), x5 = __shfl_xor((int)a5,32);              \
    u32 x6 = __shfl_xor((int)a6,32), x7 = __shfl_xor((int)a7,32);              \
    u32x4 wb0, wb1;                                                            \
    wb0[0] = h ? x2 : a0;  wb0[1] = h ? x3 : a1;                               \
    wb0[2] = h ? a2 : x0;  wb0[3] = h ? a3 : x1;                               \
    wb1[0] = h ? x6 : a4;  wb1[1] = h ? x7 : a5;                               \
    wb1[2] = h ? a6 : x4;  wb1[3] = h ? a7 : x5;                               \
    Bf0 = __builtin_bit_cast(bf16x8, wb0);                                     \
    Bf1 = __builtin_bit_cast(bf16x8, wb1); }
#define PVA(P) {                                                               \
    __builtin_amdgcn_s_setprio(1);                                             \
    o0 = __builtin_amdgcn_mfma_f32_32x32x16_bf16(P##0, Bf0, o0, 0, 0, 0);      \
    o1 = __builtin_amdgcn_mfma_f32_32x32x16_bf16(P##1, Bf0, o1, 0, 0, 0);      \
    o0 = __builtin_amdgcn_mfma_f32_32x32x16_bf16(P##2, Bf1, o0, 0, 0, 0);      \
    o1 = __builtin_amdgcn_mfma_f32_32x32x16_bf16(P##3, Bf1, o1, 0, 0, 0);      \
    __builtin_amdgcn_s_setprio(0); }

  int tstart = kh*32, tend = tstart + 32;
  // prologue: tile tstart scores ready; K(t+1)/V(t)/V(t+1) in flight
  LDK(kA, tstart);
  QKT(sA, kA);
  LDK(kB, tstart+1);
  LDV(vA, tstart);
  LDV(vB, tstart+1);

  for (int t = tstart; t < tend; t += 2){
    int t2 = (t+2 < tend) ? t+2 : tend-1;
    int t3 = (t+3 < tend) ? t+3 : tend-1;
    QKT(sB, kB);
    LDK(kA, t2);
    SMAX(sA);
    PVA(vA);
    LDV(vA, t2);
    QKT(sA, kA);
    LDK(kB, t3);
    SMAX(sB);
    PVA(vB);
    LDV(vB, t3);
  }

#undef LDK
#undef LDV
#undef QKT
#undef SMAX
#undef PVA

  // ---- merge wave pairs (kh=0 with kh=1 of the same qg) ----
  int slot = w >> 1;
  if (kh){
    #pragma unroll
    for (int j = 0; j < 4; ++j){
      *(float4*)&smrg[slot][l][j*4]      = make_float4(o0[j*4+0], o0[j*4+1], o0[j*4+2], o0[j*4+3]);
      *(float4*)&smrg[slot][l][16 + j*4] = make_float4(o1[j*4+0], o1[j*4+1], o1[j*4+2], o1[j*4+3]);
    }
    smrg[slot][l][32] = m;
    smrg[slot][l][33] = lsum;
  }
  __syncthreads();
  if (!kh){
    float mb = smrg[slot][l][32], lb = smrg[slot][l][33];
    float M  = fmaxf(m, mb);
    float aA = __builtin_amdgcn_exp2f(m  - M);
    float aB = __builtin_amdgcn_exp2f(mb - M);
    float inv = 1.f / (lsum*aA + lb*aB);
    float cA = aA*inv, cB = aB*inv;
    int b_ = bh >> 3, hh = bh & 7;
    size_t obase = ((size_t)(b_*2048) + q0 + l31)*512 + hh*64 + 4*h;
    #pragma unroll
    for (int s4 = 0; s4 < 4; ++s4){
      float4 ob = *(float4*)&smrg[slot][l][s4*4];
      ushort4 st;
      st.x = f2bf(o0[s4*4+0]*cA + ob.x*cB);
      st.y = f2bf(o0[s4*4+1]*cA + ob.y*cB);
      st.z = f2bf(o0[s4*4+2]*cA + ob.z*cB);
      st.w = f2bf(o0[s4*4+3]*cA + ob.w*cB);
      *(ushort4*)(ao + obase + s4*8) = st;
    }
    #pragma unroll
    for (int s4 = 0; s4 < 4; ++s4){
      float4 ob = *(float4*)&smrg[slot][l][16 + s4*4];
      ushort4 st;
      st.x = f2bf(o1[s4*4+0]*cA + ob.x*cB);
      st.y = f2bf(o1[s4*4+1]*cA + ob.y*cB);
      st.z = f2bf(o1[s4*4+2]*cA + ob.z*cB);
      st.w = f2bf(o1[s4*4+3]*cA + ob.w*cB);
      *(ushort4*)(ao + obase + 32 + s4*8) = st;
    }
  }
}

extern "C" void kernel_launch(void* const* d_in, const int* in_sizes, int n_in,
                              void* d_out, int out_size, void* d_ws, size_t ws_size,
                              hipStream_t stream) {
  const float* x    = (const float*)d_in[0];
  const float* gw   = (const float*)d_in[1];
  const float* gb   = (const float*)d_in[2];
  const float* wqkv = (const float*)d_in[3];
  const float* wout = (const float*)d_in[4];
  const float* bout = (const float*)d_in[5];
  float* out = (float*)d_out;
  char* ws = (char*)d_ws;

  // workspace layout (bytes) — total 42 MB
  const size_t MB8 = (size_t)4*512*2048*2;          // 8,388,608
  u16* ao  = (u16*)(ws);                            // attn output [b][l][512]
  u16* nxT = (u16*)(ws + MB8);                      // [b][l][512]
  u16* wqb = (u16*)(ws + 2*MB8);                    // 1,572,864
  u16* wob = (u16*)(ws + 2*MB8 + 1572864);          // 524,288
  u16* qT  = (u16*)(ws + 2*MB8 + 2097152);          // 3 x 8MB: qT, kF, vF
  u16* kF  = qT + (size_t)4*8*2048*64;
  u16* vF  = kF + (size_t)4*8*2048*64;
  // gn scratch: aliases qT region (dead until QKV gemm, which runs after)
  float2* pstat = (float2*)qT;                      // 512 float2

  pre_kernel<<<1536, 256, 0, stream>>>(x, pstat, wqkv, wout, wqb, wob);
  normtrans_kernel<<<dim3(32, 8, 4), 256, 0, stream>>>(x, pstat, gw, gb, nxT);
  gemm_kernel<0><<<dim3(16, 12, 4), 256, 0, stream>>>(wqb, nxT, qT, kF, vF,
                                                      nullptr, nullptr, nullptr);
  attn_kernel<<<1024, 256, 0, stream>>>(qT, kF, vF, ao);
  gemm_kernel<1><<<dim3(16, 4, 4), 256, 0, stream>>>(wob, ao, nullptr, nullptr, nullptr,
                                                     bout, x, out);
}

// Round 11
// 173.086 us; speedup vs baseline: 1.4377x; 1.4377x over previous
//
#include <hip/hip_runtime.h>

#define DEVI __device__ __forceinline__

typedef unsigned short u16;
typedef unsigned int u32;
typedef __attribute__((ext_vector_type(8))) __bf16 bf16x8;
typedef __attribute__((ext_vector_type(2))) __bf16 bf16x2;
typedef __attribute__((ext_vector_type(4))) float f32x4;
typedef __attribute__((ext_vector_type(16))) float f32x16;
typedef __attribute__((ext_vector_type(4))) u32 u32x4;

DEVI u16 f2bf(float f){
  u32 u = __float_as_uint(f);
  return (u16)((u + 0x7FFFu + ((u >> 16) & 1u)) >> 16);
}
DEVI u32 pk2(float lo, float hi){
  bf16x2 t; t[0] = (__bf16)lo; t[1] = (__bf16)hi;
  return __builtin_bit_cast(u32, t);
}

// ------ fused pre: gnstat (blocks 0..511) + weight cast (blocks 512..1535) ------
__global__ __launch_bounds__(256) void pre_kernel(const float* __restrict__ x,
                                                  float2* __restrict__ pstat,
                                                  const float* __restrict__ wq,
                                                  const float* __restrict__ wo,
                                                  u16* __restrict__ wqb,
                                                  u16* __restrict__ wob){
  int bid = blockIdx.x, tid = threadIdx.x;
  if (bid < 512){
    int bg = bid >> 2, qt = bid & 3;
    const float4* xin = (const float4*)(x + (size_t)bg*32768 + qt*8192);
    float s1 = 0.f, s2 = 0.f;
    #pragma unroll
    for (int i = 0; i < 8; ++i){
      float4 v = xin[tid + i*256];
      s1 += v.x + v.y + v.z + v.w;
      s2 += v.x*v.x + v.y*v.y + v.z*v.z + v.w*v.w;
    }
    __shared__ float red[8];
    int lane = tid & 63, w = tid >> 6;
    for (int off = 32; off; off >>= 1){
      s1 += __shfl_down(s1, off);
      s2 += __shfl_down(s2, off);
    }
    if (lane == 0){ red[w] = s1; red[4 + w] = s2; }
    __syncthreads();
    if (tid == 0){
      pstat[bid] = make_float2(red[0]+red[1]+red[2]+red[3],
                               red[4]+red[5]+red[6]+red[7]);
    }
  } else {
    int t = (bid - 512) * 256 + tid;          // 262144 float4 tasks
    const int NQ4 = (1536*512)/4;             // 196608
    float4 v; u16* dst;
    if (t < NQ4){ v = ((const float4*)wq)[t]; dst = wqb + t*4; }
    else        { int u_ = t - NQ4; v = ((const float4*)wo)[u_]; dst = wob + u_*4; }
    ushort4 s;
    s.x = f2bf(v.x); s.y = f2bf(v.y); s.z = f2bf(v.z); s.w = f2bf(v.w);
    *(ushort4*)dst = s;
  }
}

// ------- normalize + transpose (group stats inlined from pstat) -------
__global__ __launch_bounds__(256) void normtrans_kernel(const float* __restrict__ x,
                                                        const float2* __restrict__ pstat,
                                                        const float* __restrict__ gw,
                                                        const float* __restrict__ gb,
                                                        u16* __restrict__ nxT){
  int b = blockIdx.z, c0 = blockIdx.y * 64, l0 = blockIdx.x * 64;
  __shared__ u16 T[64][72];
  int tid = threadIdx.x;
  #pragma unroll
  for (int rep = 0; rep < 2; ++rep){
    int task = tid + rep*256;
    int r = task >> 3, cc = task & 7;          // channel row r, l-chunk cc
    int ch = c0 + r;
    int bg = b*32 + (ch >> 4);
    float s1 = 0.f, s2 = 0.f;
    #pragma unroll
    for (int i = 0; i < 4; ++i){
      float2 p = pstat[bg*4 + i];
      s1 += p.x; s2 += p.y;
    }
    float mu = s1 * (1.f/32768.f);
    float rsg = rsqrtf(s2 * (1.f/32768.f) - mu*mu + 1e-5f);
    float ga = gw[ch] * rsg;
    float be = gb[ch] - mu * ga;
    const float4* src = (const float4*)(x + ((size_t)(b*512 + ch))*2048 + l0 + cc*8);
    float4 v0 = src[0], v1 = src[1];
    ushort4 o0, o1;
    o0.x = f2bf(v0.x*ga + be); o0.y = f2bf(v0.y*ga + be);
    o0.z = f2bf(v0.z*ga + be); o0.w = f2bf(v0.w*ga + be);
    o1.x = f2bf(v1.x*ga + be); o1.y = f2bf(v1.y*ga + be);
    o1.z = f2bf(v1.z*ga + be); o1.w = f2bf(v1.w*ga + be);
    *(ushort4*)&T[r][cc*8]     = o0;
    *(ushort4*)&T[r][cc*8 + 4] = o1;
  }
  __syncthreads();
  #pragma unroll
  for (int rep = 0; rep < 2; ++rep){
    int task = tid + rep*256;
    int r = task >> 3, cc = task & 7;          // r = local l, cc = c-chunk
    u16 tmp[8];
    #pragma unroll
    for (int i = 0; i < 8; ++i) tmp[i] = T[cc*8 + i][r];
    *(uint4*)(nxT + ((size_t)(b*2048 + l0 + r))*512 + c0 + cc*8) = *(uint4*)tmp;
  }
}

// ---------------- GEMM: C[o][l] = sum_c A[o][c] * B[l][c]^T  (bf16 MFMA) ----
// BK=64 staged per barrier pair.
// MODE 0 epilogue: q -> qT [b][h][l][64] (scaled); k -> kF, v -> vF fragment order.
// MODE 1: epilogue adds b_out[o] + x residual, writes fp32 d_out[b][o][l].
template<int MODE>
__global__ __launch_bounds__(256) void gemm_kernel(const u16* __restrict__ A,
                                                   const u16* __restrict__ Bm,
                                                   u16* __restrict__ q_o,
                                                   u16* __restrict__ k_o,
                                                   u16* __restrict__ v_o,
                                                   const float* __restrict__ bo,
                                                   const float* __restrict__ xres,
                                                   float* __restrict__ out){
  int b  = blockIdx.z;
  int n0 = blockIdx.x * 128, m0 = blockIdx.y * 128;
  int tid = threadIdx.x, w = tid >> 6, lane = tid & 63, lq = lane >> 4, lr = lane & 15;
  int wm = (w >> 1) * 64, wn = (w & 1) * 64;
  __shared__ u16 Al[2][128][40], Bl[2][128][40];
  f32x4 acc[4][4] = {};
  const u16* Bb = Bm + (size_t)b * 2048 * 512;

  for (int k0 = 0; k0 < 512; k0 += 64){
    #pragma unroll
    for (int rep = 0; rep < 4; ++rep){
      int task = tid + rep*256;                // 1024 tasks: 128 rows x 8 kc
      int row = task >> 3, kc = task & 7;
      *(uint4*)&Al[kc>>2][row][(kc&3)*8] = *(const uint4*)(A  + (size_t)(m0+row)*512 + k0 + kc*8);
      *(uint4*)&Bl[kc>>2][row][(kc&3)*8] = *(const uint4*)(Bb + (size_t)(n0+row)*512 + k0 + kc*8);
    }
    __syncthreads();
    #pragma unroll
    for (int half = 0; half < 2; ++half){
      bf16x8 af[4], bfr[4];
      #pragma unroll
      for (int i = 0; i < 4; ++i) af[i]  = *(const bf16x8*)&Al[half][wm + i*16 + lr][lq*8];
      #pragma unroll
      for (int j = 0; j < 4; ++j) bfr[j] = *(const bf16x8*)&Bl[half][wn + j*16 + lr][lq*8];
      #pragma unroll
      for (int i = 0; i < 4; ++i)
        #pragma unroll
        for (int j = 0; j < 4; ++j)
          acc[i][j] = __builtin_amdgcn_mfma_f32_16x16x32_bf16(af[i], bfr[j], acc[i][j], 0, 0, 0);
    }
    __syncthreads();
  }

  if (MODE == 0){
    const float QSCALE = 0.125f * 1.4426950408889634f;   // fold log2e for exp2 softmax
    #pragma unroll
    for (int i = 0; i < 4; ++i){
      int o0  = m0 + wm + i*16 + lq*4;          // 4 consecutive o, aligned
      int cls = o0 >> 9;                        // 0=q 1=k 2=v
      int hh  = (o0 >> 6) & 7;
      int d0  = o0 & 63;
      size_t hbase = (size_t)(b*8+hh) * 2048 * 64;
      #pragma unroll
      for (int j = 0; j < 4; ++j){
        int l = n0 + wn + j*16 + lr;            // column index (seq pos / k-idx)
        f32x4 v = acc[i][j];
        if (cls == 0){
          ushort4 s;
          s.x = f2bf(v[0]*QSCALE); s.y = f2bf(v[1]*QSCALE);
          s.z = f2bf(v[2]*QSCALE); s.w = f2bf(v[3]*QSCALE);
          *(ushort4*)(q_o + hbase + (size_t)l*64 + d0) = s;
        } else if (cls == 1){
          size_t off = (size_t)(((l>>5)*4 + (d0>>4)))*512
                     + ((d0>>3)&1)*256 + (l&31)*8 + (d0&7);
          ushort4 s;
          s.x = f2bf(v[0]); s.y = f2bf(v[1]); s.z = f2bf(v[2]); s.w = f2bf(v[3]);
          *(ushort4*)(k_o + hbase + off) = s;
        } else {
          size_t off = (size_t)(((l>>4)*2 + (d0>>5)))*512
                     + ((l>>3)&1)*256 + (l&7);
          #pragma unroll
          for (int r = 0; r < 4; ++r)
            v_o[hbase + off + ((d0+r)&31)*8] = f2bf(v[r]);
        }
      }
    }
  } else {
    #pragma unroll
    for (int i = 0; i < 4; ++i){
      int o0 = m0 + wm + i*16 + lq*4;
      #pragma unroll
      for (int j = 0; j < 4; ++j){
        int l = n0 + wn + j*16 + lr;
        #pragma unroll
        for (int r = 0; r < 4; ++r){
          int o = o0 + r;
          size_t idx = ((size_t)b*512 + o)*2048 + l;
          out[idx] = acc[i][j][r] + bo[o] + xres[idx];
        }
      }
    }
  }
}

// ------- flash attention: 32x32 MFMA, no LDS, software-pipelined ----------
// Round-7 structure (known-good): 512 blocks, full K per wave, lockstep
// streaming keeps K/V L2-resident (12 MB fetch). Do NOT K-split (round-9
// lesson: it breaks L2 phase-coherence and goes HBM-bound at 135 MB).
__global__ __launch_bounds__(256, 2) void attn_kernel(const u16* __restrict__ qT,
                                                      const u16* __restrict__ kF,
                                                      const u16* __restrict__ vF,
                                                      u16* __restrict__ ao){
  int flat = blockIdx.x;              // 0..511
  int xcd = flat & 7, tt = flat >> 3; // 4 heads per XCD for K/V L2 locality
  int bh = xcd*4 + (tt & 3);          // 0..31
  int qb = tt >> 2;                   // 0..15
  int tid = threadIdx.x, w = tid >> 6, l = tid & 63;
  int l31 = l & 31, h = l >> 5;
  int q0 = qb*128 + w*32;
  size_t hoff = (size_t)bh * 2048 * 64;

  // Q as B-operand: B[col=q=l31][kc=8h+e] = Q[q0+l31][ds*16+8h+e]
  const u16* qp = qT + hoff + (size_t)(q0 + l31)*64 + 8*h;
  bf16x8 qf0 = *(const bf16x8*)(qp);
  bf16x8 qf1 = *(const bf16x8*)(qp + 16);
  bf16x8 qf2 = *(const bf16x8*)(qp + 32);
  bf16x8 qf3 = *(const bf16x8*)(qp + 48);

  const u16* kbase = kF + hoff + (size_t)l*8;
  const u16* vbase = vF + hoff + (size_t)l*8;

  f32x16 o0 = {}, o1 = {};
  float m = -1e30f, lsum = 0.f;

  bf16x8 kA0,kA1,kA2,kA3, kB0,kB1,kB2,kB3;
  bf16x8 vA0,vA1,vA2,vA3, vB0,vB1,vB2,vB3;
  f32x16 sA, sB;
  bf16x8 Bf0, Bf1;

#define LDK(P, t) { const u16* kt_ = kbase + (t)*2048;                         \
    P##0 = *(const bf16x8*)(kt_);        P##1 = *(const bf16x8*)(kt_ + 512);   \
    P##2 = *(const bf16x8*)(kt_ + 1024); P##3 = *(const bf16x8*)(kt_ + 1536); }
#define LDV(P, t) { const u16* vt_ = vbase + (t)*2048;                         \
    P##0 = *(const bf16x8*)(vt_);        P##1 = *(const bf16x8*)(vt_ + 512);   \
    P##2 = *(const bf16x8*)(vt_ + 1024); P##3 = *(const bf16x8*)(vt_ + 1536); }
#define QKT(S, P) {                                                            \
    S = (f32x16){};                                                            \
    __builtin_amdgcn_s_setprio(1);                                             \
    S = __builtin_amdgcn_mfma_f32_32x32x16_bf16(P##0, qf0, S, 0, 0, 0);        \
    S = __builtin_amdgcn_mfma_f32_32x32x16_bf16(P##1, qf1, S, 0, 0, 0);        \
    S = __builtin_amdgcn_mfma_f32_32x32x16_bf16(P##2, qf2, S, 0, 0, 0);        \
    S = __builtin_amdgcn_mfma_f32_32x32x16_bf16(P##3, qf3, S, 0, 0, 0);        \
    __builtin_amdgcn_s_setprio(0); }
#define SMAX(S) { \
    float c0 = fmaxf(S[0],S[1]),  c1 = fmaxf(S[2],S[3]);                       \
    float c2 = fmaxf(S[4],S[5]),  c3 = fmaxf(S[6],S[7]);                       \
    float c4 = fmaxf(S[8],S[9]),  c5 = fmaxf(S[10],S[11]);                     \
    float c6 = fmaxf(S[12],S[13]),c7 = fmaxf(S[14],S[15]);                     \
    c0 = fmaxf(c0,c1); c2 = fmaxf(c2,c3); c4 = fmaxf(c4,c5); c6 = fmaxf(c6,c7);\
    c0 = fmaxf(c0,c2); c4 = fmaxf(c4,c6); c0 = fmaxf(c0,c4);                   \
    c0 = fmaxf(c0, __shfl_xor(c0, 32));                                        \
    if (__any(c0 > m + 8.f)){                                                  \
      float nm = fmaxf(m, c0);                                                 \
      float alpha = __builtin_amdgcn_exp2f(m - nm);                            \
      m = nm; lsum *= alpha;                                                   \
      _Pragma("unroll")                                                        \
      for (int i = 0; i < 16; ++i){ o0[i] *= alpha; o1[i] *= alpha; }          \
    }                                                                          \
    float p[16];                                                               \
    _Pragma("unroll")                                                          \
    for (int i = 0; i < 16; ++i) p[i] = __builtin_amdgcn_exp2f(S[i] - m);      \
    float t0 = p[0]+p[1],  t1 = p[2]+p[3],  t2 = p[4]+p[5],  t3 = p[6]+p[7];   \
    float t4 = p[8]+p[9],  t5 = p[10]+p[11],t6 = p[12]+p[13],t7 = p[14]+p[15]; \
    t0 += t1; t2 += t3; t4 += t5; t6 += t7; t0 += t2; t4 += t6; t0 += t4;      \
    lsum += t0 + __shfl_xor(t0, 32);                                           \
    u32 a0 = pk2(p[0],p[1]),   a1 = pk2(p[2],p[3]);                            \
    u32 a2 = pk2(p[4],p[5]),   a3 = pk2(p[6],p[7]);                            \
    u32 a4 = pk2(p[8],p[9]),   a5 = pk2(p[10],p[11]);                          \
    u32 a6 = pk2(p[12],p[13]), a7 = pk2(p[14],p[15]);                          \
    u32 x0 = __shfl_xor((int)a0,32), x1 = __shfl_xor((int)a1,32);              \
    u32 x2 = __shfl_xor((int)a2,32), x3 = __shfl_xor((int)a3,32);              \
    u32 x4 = __shfl_xor((int)a4,32), x5 = __shfl_xor((int)a5,32);              \
    u32 x6 = __shfl_xor((int)a6,32), x7 = __shfl_xor((int)a7,32);              \
    u32x4 wb0, wb1;                                                            \
    wb0[0] = h ? x2 : a0;  wb0[1] = h ? x3 : a1;                               \
    wb0[2] = h ? a2 : x0;  wb0[3] = h ? a3 : x1;                               \
    wb1[0] = h ? x6 : a4;  wb1[1] = h ? x7 : a5;                               \
    wb1[2] = h ? a6 : x4;  wb1[3] = h ? a7 : x5;                               \
    Bf0 = __builtin_bit_cast(bf16x8, wb0);                                     \
    Bf1 = __builtin_bit_cast(bf16x8, wb1); }
#define PVA(P) {                                                               \
    __builtin_amdgcn_s_setprio(1);                                             \
    o0 = __builtin_amdgcn_mfma_f32_32x32x16_bf16(P##0, Bf0, o0, 0, 0, 0);      \
    o1 = __builtin_amdgcn_mfma_f32_32x32x16_bf16(P##1, Bf0, o1, 0, 0, 0);      \
    o0 = __builtin_amdgcn_mfma_f32_32x32x16_bf16(P##2, Bf1, o0, 0, 0, 0);      \
    o1 = __builtin_amdgcn_mfma_f32_32x32x16_bf16(P##3, Bf1, o1, 0, 0, 0);      \
    __builtin_amdgcn_s_setprio(0); }

  // prologue: tile0 scores ready; K1/V0/V1 in flight
  LDK(kA, 0);
  QKT(sA, kA);
  LDK(kB, 1);
  LDV(vA, 0);
  LDV(vB, 1);

  for (int t = 0; t < 64; t += 2){
    int t2 = (t+2 < 64) ? t+2 : 63;
    int t3 = (t+3 < 64) ? t+3 : 63;
    // stage 1: process tile t (sA), score tile t+1, prefetch t+2
    QKT(sB, kB);
    LDK(kA, t2);
    SMAX(sA);
    PVA(vA);
    LDV(vA, t2);
    // stage 2: process tile t+1 (sB), score tile t+2, prefetch t+3
    QKT(sA, kA);
    LDK(kB, t3);
    SMAX(sB);
    PVA(vB);
    LDV(vB, t3);
  }

#undef LDK
#undef LDV
#undef QKT
#undef SMAX
#undef PVA

  // epilogue: O[q=l31][d = dh*32 + s4*8 + 4h + r]
  float inv = 1.f / lsum;
  int b_ = bh >> 3, hh = bh & 7;
  size_t obase = ((size_t)(b_*2048) + q0 + l31)*512 + hh*64 + 4*h;
  #pragma unroll
  for (int s4 = 0; s4 < 4; ++s4){
    ushort4 st;
    st.x = f2bf(o0[s4*4+0]*inv); st.y = f2bf(o0[s4*4+1]*inv);
    st.z = f2bf(o0[s4*4+2]*inv); st.w = f2bf(o0[s4*4+3]*inv);
    *(ushort4*)(ao + obase + s4*8) = st;
  }
  #pragma unroll
  for (int s4 = 0; s4 < 4; ++s4){
    ushort4 st;
    st.x = f2bf(o1[s4*4+0]*inv); st.y = f2bf(o1[s4*4+1]*inv);
    st.z = f2bf(o1[s4*4+2]*inv); st.w = f2bf(o1[s4*4+3]*inv);
    *(ushort4*)(ao + obase + 32 + s4*8) = st;
  }
}

extern "C" void kernel_launch(void* const* d_in, const int* in_sizes, int n_in,
                              void* d_out, int out_size, void* d_ws, size_t ws_size,
                              hipStream_t stream) {
  const float* x    = (const float*)d_in[0];
  const float* gw   = (const float*)d_in[1];
  const float* gb   = (const float*)d_in[2];
  const float* wqkv = (const float*)d_in[3];
  const float* wout = (const float*)d_in[4];
  const float* bout = (const float*)d_in[5];
  float* out = (float*)d_out;
  char* ws = (char*)d_ws;

  // workspace layout (bytes) — total 42 MB
  const size_t MB8 = (size_t)4*512*2048*2;          // 8,388,608
  u16* ao  = (u16*)(ws);                            // attn output [b][l][512]
  u16* nxT = (u16*)(ws + MB8);                      // [b][l][512]
  u16* wqb = (u16*)(ws + 2*MB8);                    // 1,572,864
  u16* wob = (u16*)(ws + 2*MB8 + 1572864);          // 524,288
  u16* qT  = (u16*)(ws + 2*MB8 + 2097152);          // 3 x 8MB: qT, kF, vF
  u16* kF  = qT + (size_t)4*8*2048*64;
  u16* vF  = kF + (size_t)4*8*2048*64;
  // gn scratch: aliases qT region (dead until QKV gemm, which runs after)
  float2* pstat = (float2*)qT;                      // 512 float2

  pre_kernel<<<1536, 256, 0, stream>>>(x, pstat, wqkv, wout, wqb, wob);
  normtrans_kernel<<<dim3(32, 8, 4), 256, 0, stream>>>(x, pstat, gw, gb, nxT);
  gemm_kernel<0><<<dim3(16, 12, 4), 256, 0, stream>>>(wqb, nxT, qT, kF, vF,
                                                      nullptr, nullptr, nullptr);
  attn_kernel<<<512, 256, 0, stream>>>(qT, kF, vF, ao);
  gemm_kernel<1><<<dim3(16, 4, 4), 256, 0, stream>>>(wob, ao, nullptr, nullptr, nullptr,
                                                     bout, x, out);
}